// Round 10
// baseline (259.212 us; speedup 1.0000x reference)
//
#include <hip/hip_runtime.h>
#include <math.h>

#define NS 200
#define FEAT 64
#define GRIDN 128

__device__ __forceinline__ float rl(float v, int l) {
    return __uint_as_float(
        __builtin_amdgcn_readlane(__float_as_uint(v), (unsigned)l));
}

// Unconditional-safe: corner indices are clamped to [0,127]; out-of-range
// coords give valid=false -> contribution 0 (exact reference semantics).
__device__ __forceinline__ float trilinear(const float* __restrict__ g,
                                           float x, float y, float z) {
    const float W = 128.f, H = 128.f, D = 128.f;
    float gx = ((x + 1.f) * W - 1.f) * 0.5f;
    float gy = ((y + 1.f) * H - 1.f) * 0.5f;
    float gz = ((z + 1.f) * D - 1.f) * 0.5f;
    float x0 = floorf(gx), y0 = floorf(gy), z0 = floorf(gz);
    float out = 0.f;
#pragma unroll
    for (int dz = 0; dz < 2; ++dz)
#pragma unroll
        for (int dy = 0; dy < 2; ++dy)
#pragma unroll
            for (int dx = 0; dx < 2; ++dx) {
                float xi = x0 + dx, yi = y0 + dy, zi = z0 + dz;
                float w = (1.f - fabsf(gx - xi)) * (1.f - fabsf(gy - yi)) *
                          (1.f - fabsf(gz - zi));
                bool valid = (xi >= 0.f) && (xi < W) && (yi >= 0.f) &&
                             (yi < H) && (zi >= 0.f) && (zi < D);
                int xc = (int)fminf(fmaxf(xi, 0.f), 127.f);
                int yc = (int)fminf(fmaxf(yi, 0.f), 127.f);
                int zc = (int)fminf(fmaxf(zi, 0.f), 127.f);
                float v = valid ? g[(zc * GRIDN + yc) * GRIDN + xc] : 0.f;
                out += w * v;
            }
    return out;
}

// ws layout: ws[0..63] = w2s = fw2@sw ; ws[64] = fb2@sw + sb ;
// ((int*)ws)[66] = persistent-block ray queue counter (zeroed here).
__global__ __launch_bounds__(128) void precomp(const float* __restrict__ fw2,
                                               const float* __restrict__ sw,
                                               const float* __restrict__ fb2,
                                               const float* __restrict__ sb,
                                               float* __restrict__ ws) {
    int tid = threadIdx.x;
    if (tid < FEAT) {
        float a = 0.f;
        for (int j = 0; j < FEAT; ++j) a += fw2[tid * FEAT + j] * sw[j];
        ws[tid] = a;
    } else if (tid == FEAT) {
        float a = sb[0];
        for (int j = 0; j < FEAT; ++j) a += fb2[j] * sw[j];
        ws[FEAT] = a;
    } else if (tid == FEAT + 1) {
        ((int*)ws)[66] = 0;  // ray queue counter
    }
}

__global__ __launch_bounds__(256) void render(
    const float* __restrict__ ro, const float* __restrict__ rd,
    const float* __restrict__ gvol, const float* __restrict__ aabb,
    const float* __restrict__ fw1, const float* __restrict__ fb1,
    const float* __restrict__ fw2, const float* __restrict__ fb2,
    const float* __restrict__ rw1, const float* __restrict__ rb1,
    const float* __restrict__ rw2, const float* __restrict__ rb2,
    float* __restrict__ ws, float* __restrict__ out, int n_rays) {
    __shared__ float s_sig[NS];  // per-sample sigma (0 if masked)
    __shared__ float s_w[NS];    // effective per-sample weights
    __shared__ int s_list[NS];   // active sample indices
    __shared__ float s_wsum[4];  // per-wave scan totals
    __shared__ float s_acc[4][3];
    __shared__ int s_cnt;
    __shared__ int s_ray;

    const int tid = threadIdx.x;
    const int f = tid & 63, wv = tid >> 6;
    int* qctr = (int*)ws + 66;

    const float a0x = aabb[0], a0y = aabb[1], a0z = aabb[2];
    const float a1x = aabb[3], a1y = aabb[4], a1z = aabb[5];
    const float ex = a1x - a0x, ey = a1y - a0y, ez = a1z - a0z;
    const float step = sqrtf(ex * ex + ey * ey + ez * ez) / (float)NS;
    const float cbias = ws[FEAT];
    const float we = ws[f];
    const float wa = fw1[f], wb = fw1[64 + f], wc = fw1[128 + f];
    const float wd = fb1[f];
    const float fb2f = fb2[f];
    const float w20 = rw2[f * 3 + 0], w21 = rw2[f * 3 + 1],
                w22 = rw2[f * 3 + 2];
    const float r20 = rb2[0], r21 = rb2[1], r22 = rb2[2];
    const float rw1d0 = rw1[64 * FEAT + f], rw1d1 = rw1[65 * FEAT + f],
                rw1d2 = rw1[66 * FEAT + f], rb1f = rb1[f];
    const float i2x = 2.f / ex, i2y = 2.f / ey, i2z = 2.f / ez;

    for (;;) {
        if (tid == 0) {
            s_ray = atomicAdd(qctr, 1);
            s_cnt = 0;
        }
        if (tid < NS) s_sig[tid] = 0.f;
        __syncthreads();
        const int ray = s_ray;
        if (ray >= n_rays) return;  // queue drained (block-uniform)

        // ---- phase A: ray geometry + slab rejection ----
        const float ox = ro[ray * 3 + 0], oy = ro[ray * 3 + 1],
                    oz = ro[ray * 3 + 2];
        const float dx = rd[ray * 3 + 0], dy = rd[ray * 3 + 1],
                    dz = rd[ray * 3 + 2];
        const float ddx = (dx == 0.f) ? dx + 1e-9f : dx;
        const float ddy = (dy == 0.f) ? dy + 1e-9f : dy;
        const float ddz = (dz == 0.f) ? dz + 1e-9f : dz;
        const float r1x = (a0x - ox) / ddx, r2x = (a1x - ox) / ddx;
        const float r1y = (a0y - oy) / ddy, r2y = (a1y - oy) / ddy;
        const float r1z = (a0z - oz) / ddz, r2z = (a1z - oz) / ddz;
        const float t_lo =
            fmaxf(fmaxf(fminf(r1x, r2x), fminf(r1y, r2y)), fminf(r1z, r2z));
        const float t_hi =
            fminf(fminf(fmaxf(r1x, r2x), fmaxf(r1y, r2y)), fmaxf(r1z, r2z));
        float t_min = fminf(fmaxf(t_lo, 0.f), 100000.f);
        if (t_min > t_hi + step || t_min + 199.f * step < t_lo - step) {
            if (tid < 3) out[ray * 3 + tid] = 0.f;
            __syncthreads();  // all lanes read s_ray before next-iter write
            continue;
        }

        // h_j(t) = A_j + t*B_j (per-lane feature slice)
        const float cx = (ox - a0x) * i2x - 1.f;
        const float cy = (oy - a0y) * i2y - 1.f;
        const float cz = (oz - a0z) * i2z - 1.f;
        const float gx = dx * i2x, gy = dy * i2y, gz = dz * i2z;
        const float Af = cx * wa + cy * wb + cz * wc + wd;
        const float Bf = gx * wa + gy * wb + gz * wc;

        int s_begin = (int)floorf((t_lo - t_min) / step) - 1;
        if (s_begin < 0) s_begin = 0;
        int s_end = (int)ceilf((t_hi - t_min) / step) + 1;
        if (s_end > NS - 1) s_end = NS - 1;

        // ---- phase B: per-wave chunk, 2 samples in flight, wave-uniform ----
        const int span = s_end - s_begin + 1;
        const int chunk = (span + 3) >> 2;
        const int b0 = s_begin + wv * chunk;
        int b1 = b0 + chunk - 1;
        if (b1 > s_end) b1 = s_end;
        const int hc = (b1 >= b0) ? ((b1 - b0 + 2) >> 1) : 0;
        for (int k = 0; k < hc; ++k) {
            const int sA = b0 + k;
            const int sB = b0 + hc + k;
            const bool vB = sB <= b1;
            const float tA = t_min + (float)sA * step;
            const float tB = t_min + (float)(vB ? sB : sA) * step;
            const float pAx = ox + dx * tA, pAy = oy + dy * tA,
                        pAz = oz + dz * tA;
            const float pBx = ox + dx * tB, pBy = oy + dy * tB,
                        pBz = oz + dz * tB;
            const bool inA = (pAx >= a0x) & (pAx <= a1x) & (pAy >= a0y) &
                             (pAy <= a1y) & (pAz >= a0z) & (pAz <= a1z);
            const bool inB = (pBx >= a0x) & (pBx <= a1x) & (pBy >= a0y) &
                             (pBy <= a1y) & (pBz >= a0z) & (pBz <= a1z);
            // unconditional trilinear: 16 loads in flight, clamped-safe
            const float occA =
                trilinear(gvol, (pAx - a0x) / ex * 2.f - 1.f,
                          (pAy - a0y) / ey * 2.f - 1.f,
                          (pAz - a0z) / ez * 2.f - 1.f);
            const float occB =
                trilinear(gvol, (pBx - a0x) / ex * 2.f - 1.f,
                          (pBy - a0y) / ey * 2.f - 1.f,
                          (pBz - a0z) / ez * 2.f - 1.f);
            const bool mA = inA && (occA > 0.01f);          // wave-uniform
            const bool mB = vB && inB && (occB > 0.01f);    // wave-uniform
            if (mA | mB) {
                float pA = fmaxf(Af + tA * Bf, 0.f) * we;
                float pB = fmaxf(Af + tB * Bf, 0.f) * we;
#pragma unroll
                for (int off = 32; off > 0; off >>= 1) {
                    pA += __shfl_xor(pA, off);
                    pB += __shfl_xor(pB, off);
                }
                if (f == 0) {
                    if (mA) s_sig[sA] = pA + cbias;
                    if (mB) s_sig[sB] = pB + cbias;
                }
            }
        }
        __syncthreads();

        // ---- phase C: block scan of log_a -> weights + compaction ----
        float sig = (tid < NS) ? s_sig[tid] : 0.f;
        float la = -sig * step;
        float run = la;
#pragma unroll
        for (int off = 1; off < 64; off <<= 1) {
            float v = __shfl_up(run, off);
            if (f >= off) run += v;
        }
        if (f == 63) s_wsum[wv] = run;
        __syncthreads();
        float offs = 0.f;
        for (int k = 0; k < wv; ++k) offs += s_wsum[k];
        run += offs;
        if (tid < NS) {
            float trans = expf(run - la);
            float e = expf(la);
            float w = (trans > 1e-4f) ? trans * (1.f - e) : 0.f;
            s_w[tid] = w;
            if (w != 0.f) {
                int p = atomicAdd(&s_cnt, 1);
                s_list[p] = tid;
            }
        }
        __syncthreads();
        const int cnt = s_cnt;
        if (cnt == 0) {
            if (tid < 3) out[ray * 3 + tid] = 0.f;
            __syncthreads();
            continue;
        }

        // ---- phase E: rgb head, 2 samples/wave/iter, shared weight loads ---
        const float rh_dir = dx * rw1d0 + dy * rw1d1 + dz * rw1d2 + rb1f;
        float a0 = 0.f, a1 = 0.f, a2 = 0.f;
        for (int i0 = 2 * wv; i0 < cnt; i0 += 8) {
            const bool hasB = (i0 + 1) < cnt;               // wave-uniform
            const int sA = s_list[i0];
            const int sB = s_list[hasB ? i0 + 1 : i0];
            const float wA = s_w[sA];
            const float wB = hasB ? s_w[sB] : 0.f;
            const float tA = t_min + (float)sA * step;
            const float tB = t_min + (float)sB * step;
            const float hA = fmaxf(Af + tA * Bf, 0.f);
            const float hB = fmaxf(Af + tB * Bf, 0.f);
            float eA0 = 0.f, eA1 = 0.f, eB0 = 0.f, eB1 = 0.f;
#pragma unroll 4
            for (int j = 0; j < FEAT; j += 2) {
                const float u0 = fw2[j * FEAT + f];
                const float u1 = fw2[(j + 1) * FEAT + f];
                eA0 += rl(hA, j) * u0;
                eB0 += rl(hB, j) * u0;
                eA1 += rl(hA, j + 1) * u1;
                eB1 += rl(hB, j + 1) * u1;
            }
            const float feA = fb2f + (eA0 + eA1);
            const float feB = fb2f + (eB0 + eB1);
            float gA0 = 0.f, gA1 = 0.f, gB0 = 0.f, gB1 = 0.f;
#pragma unroll 4
            for (int j = 0; j < FEAT; j += 2) {
                const float u0 = rw1[j * FEAT + f];
                const float u1 = rw1[(j + 1) * FEAT + f];
                gA0 += rl(feA, j) * u0;
                gB0 += rl(feB, j) * u0;
                gA1 += rl(feA, j + 1) * u1;
                gB1 += rl(feB, j + 1) * u1;
            }
            const float rhA = fmaxf(rh_dir + (gA0 + gA1), 0.f);
            const float rhB = fmaxf(rh_dir + (gB0 + gB1), 0.f);
            float qA0 = rhA * w20, qA1 = rhA * w21, qA2 = rhA * w22;
            float qB0 = rhB * w20, qB1 = rhB * w21, qB2 = rhB * w22;
#pragma unroll
            for (int off = 32; off > 0; off >>= 1) {
                qA0 += __shfl_xor(qA0, off);
                qA1 += __shfl_xor(qA1, off);
                qA2 += __shfl_xor(qA2, off);
                qB0 += __shfl_xor(qB0, off);
                qB1 += __shfl_xor(qB1, off);
                qB2 += __shfl_xor(qB2, off);
            }
            a0 += wA / (1.f + expf(-(qA0 + r20))) +
                  wB / (1.f + expf(-(qB0 + r20)));
            a1 += wA / (1.f + expf(-(qA1 + r21))) +
                  wB / (1.f + expf(-(qB1 + r21)));
            a2 += wA / (1.f + expf(-(qA2 + r22))) +
                  wB / (1.f + expf(-(qB2 + r22)));
        }
        if (f == 0) {
            s_acc[wv][0] = a0;
            s_acc[wv][1] = a1;
            s_acc[wv][2] = a2;
        }
        __syncthreads();
        if (tid == 0) {
            out[ray * 3 + 0] =
                s_acc[0][0] + s_acc[1][0] + s_acc[2][0] + s_acc[3][0];
            out[ray * 3 + 1] =
                s_acc[0][1] + s_acc[1][1] + s_acc[2][1] + s_acc[3][1];
            out[ray * 3 + 2] =
                s_acc[0][2] + s_acc[1][2] + s_acc[2][2] + s_acc[3][2];
        }
        __syncthreads();  // out-writer done; safe to recycle shared state
    }
}

extern "C" void kernel_launch(void* const* d_in, const int* in_sizes, int n_in,
                              void* d_out, int out_size, void* d_ws,
                              size_t ws_size, hipStream_t stream) {
    const float* rays_o = (const float*)d_in[0];
    const float* rays_d = (const float*)d_in[1];
    const float* grid = (const float*)d_in[2];
    const float* aabb = (const float*)d_in[3];
    const float* fw1 = (const float*)d_in[4];
    const float* fb1 = (const float*)d_in[5];
    const float* fw2 = (const float*)d_in[6];
    const float* fb2 = (const float*)d_in[7];
    const float* sw = (const float*)d_in[8];
    const float* sb = (const float*)d_in[9];
    const float* rw1 = (const float*)d_in[10];
    const float* rb1 = (const float*)d_in[11];
    const float* rw2 = (const float*)d_in[12];
    const float* rb2 = (const float*)d_in[13];
    float* out = (float*)d_out;
    float* ws = (float*)d_ws;
    const int n_rays = in_sizes[0] / 3;

    precomp<<<1, 128, 0, stream>>>(fw2, sw, fb2, sb, ws);
    render<<<2048, 256, 0, stream>>>(rays_o, rays_d, grid, aabb, fw1, fb1,
                                     fw2, fb2, rw1, rb1, rw2, rb2, ws, out,
                                     n_rays);
}